// Round 9
// baseline (271.833 us; speedup 1.0000x reference)
//
#include <hip/hip_runtime.h>

#define BBATCH 1024
#define NPAIR 512
#define PP 23      // nodes per frame
#define FF 14
#define DD 256
#define CC 23
#define APAIR 12288   // shorts per pair: 3 mtiles * 8 ks * 512

// LDS byte offsets inside k_layer's union region
#define SL_OFF 0
#define SR_OFF 23920
#define S_OFF  47840
#define GS_OFF 56304
#define DLDR_OFF 58352
#define SMEM_SZ 59104

// 16B-block swizzle within a 256-float row (64 blocks): involution
#define SWZ4(b) ((b) ^ (((b) >> 3) & 7))

typedef __attribute__((ext_vector_type(8))) short bf16x8;
typedef __attribute__((ext_vector_type(4))) float f32x4;

#define GLOAD16(gp, lp) __builtin_amdgcn_global_load_lds( \
    (const __attribute__((address_space(1))) void*)(gp),  \
    (__attribute__((address_space(3))) void*)(lp), 16, 0, 0)

__device__ __forceinline__ short f2bf_rne(float v) {
    unsigned u = __float_as_uint(v);
    unsigned r = (u + 0x7FFFu + ((u >> 16) & 1u)) >> 16;
    return (short)(unsigned short)r;
}
__device__ __forceinline__ float bf2f(short s) {
    return __uint_as_float(((unsigned)(unsigned short)s) << 16);
}

// Pair-packed A: [pair][mt(3)][ks(8)][lane(64)][e(8)] shorts.
// row r = f*23 + i (0..45), lane = (r&15) + ((k&31)>>3)*16, ks = k>>5, e = k&7, mt = r>>4.

// ---------------- weight prep (blocks 0..95) + EB (blocks 96..118) ----------------
__global__ __launch_bounds__(256) void k_prep(const float* __restrict__ Wl,
    const float* __restrict__ Wr, const float* __restrict__ E,
    const float* __restrict__ Ws1, short* __restrict__ Bh, short* __restrict__ Bl,
    float* __restrict__ EB)
{
    __shared__ float ws[DD][16];
    int t = threadIdx.x;
    if (blockIdx.x < 96) {
        int bid = blockIdx.x;            // l*32 + ntile
        int ll = bid >> 5, ntile = bid & 31;
        int n0 = ntile * 16;
        const float* W = (n0 < 256) ? (Wl + (size_t)ll * 65536) : (Wr + (size_t)ll * 65536);
        int c0 = n0 & 255;
        for (int kk = t >> 4; kk < DD; kk += 16)
            ws[kk][t & 15] = W[(size_t)kk * 256 + c0 + (t & 15)];
        __syncthreads();
        size_t base = (size_t)bid * 4096;
        for (int idx = t; idx < 4096; idx += 256) {
            int ks = idx >> 9;
            int lane = (idx >> 3) & 63;
            int e = idx & 7;
            int col = lane & 15;
            int k = ks * 32 + ((lane >> 4) << 3) + e;
            float v = ws[k][col];
            short hi = f2bf_rne(v);
            Bh[base + idx] = hi;
            Bl[base + idx] = f2bf_rne(v - bf2f(hi));
        }
    } else {
        int c = blockIdx.x - 96;
        float acc = 0.f;
        for (int k = 0; k < DD; ++k)
            acc = fmaf(E[c * DD + k], Ws1[(DD + k) * DD + t], acc);
        EB[c * DD + t] = acc;
    }
}

// ---------------- input projection -> pair-packed bf16 hi/lo ----------------
__global__ __launch_bounds__(256) void k_in_proj(const float* __restrict__ x,
    const float* __restrict__ Win, const float* __restrict__ bin,
    short* __restrict__ Ah, short* __restrict__ Al)
{
    __shared__ float xs[PP][FF];
    int t = threadIdx.x;
    int frame = blockIdx.x;
    for (int idx = t; idx < PP * FF; idx += 256)
        xs[idx / FF][idx % FF] = x[(size_t)frame * PP * FF + idx];
    __syncthreads();
    float w[FF];
#pragma unroll
    for (int f = 0; f < FF; ++f) w[f] = Win[f * DD + t];
    float bb = bin[t];
    int ks = t >> 5, lhi = ((t & 31) >> 3) << 4, e = t & 7;
    size_t pb = (size_t)(frame >> 1) * APAIR;
    int r0 = (frame & 1) * PP;
#pragma unroll
    for (int i = 0; i < PP; ++i) {
        float acc = bb;
#pragma unroll
        for (int f = 0; f < FF; ++f) acc = fmaf(xs[i][f], w[f], acc);
        int r = r0 + i;
        size_t off = pb + ((size_t)((r >> 4) * 8 + ks) << 9) + ((r & 15) + lhi) * 8 + e;
        short hi = f2bf_rne(acc);
        Ah[off] = hi;
        Al[off] = f2bf_rne(acc - bf2f(hi));
    }
}

// ---------------- fused 2-frame GATv2 layer ----------------
__global__ __launch_bounds__(512, 4) void k_layer(
    short* __restrict__ Ah, short* __restrict__ Al,
    const short* __restrict__ Bh, const short* __restrict__ Bl,
    const float* __restrict__ att, float* __restrict__ g)
{
    // union: phase1 staged A (49152 B) | phase2 sl + sro(hr/outv) + S + gsum + dldr
    __shared__ __align__(16) char smem[SMEM_SZ];
    __shared__ float satt[DD];                 // swizzled att copy
    short* lsA  = (short*)smem;
    float* sl   = (float*)(smem + SL_OFF);     // [23][260], 16B blocks XOR-swizzled
    float* sro  = (float*)(smem + SR_OFF);     // hr (swizzled) -> outv (plain)
    float* S    = (float*)(smem + S_OFF);      // [23][23][4]
    float* gsum = (float*)(smem + GS_OFF);     // [2][256]
    float* dldr = (float*)(smem + DLDR_OFF);   // dl[23][4], dr[23][4]

    int t = threadIdx.x;
    int pair = blockIdx.x;
    size_t pb = (size_t)pair * APAIR;

    if (t < DD) satt[SWZ4(t >> 2) * 4 + (t & 3)] = att[t];

    // ---- stage A (hi+lo, 48 KB) into LDS ----
    {
        const short* gAh = Ah + pb + t * 8;
        const short* gAl = Al + pb + t * 8;
#pragma unroll
        for (int pass = 0; pass < 3; ++pass) {
            GLOAD16(gAh + pass * 4096, lsA + pass * 4096 + t * 8);
            GLOAD16(gAl + pass * 4096, lsA + 12288 + pass * 4096 + t * 8);
        }
    }

    int l = t & 63, w = t >> 6;
    const short* pB_h = Bh + (size_t)(w * 4) * 4096 + l * 8;
    const short* pB_l = Bl + (size_t)(w * 4) * 4096 + l * 8;
    const short* lA_h = lsA + l * 8;
    const short* lA_l = lsA + 12288 + l * 8;

    f32x4 acc[3][4];
#pragma unroll
    for (int mt = 0; mt < 3; ++mt)
#pragma unroll
        for (int nt = 0; nt < 4; ++nt) acc[mt][nt] = (f32x4)0.0f;

    __syncthreads();   // staging complete

    // ---- GEMM: M=46(+2 pad), N=512, K=256, hi/lo 3-term ----
#pragma unroll
    for (int ks = 0; ks < 8; ++ks) {
        bf16x8 ah[3], al2[3];
#pragma unroll
        for (int mt = 0; mt < 3; ++mt) {
            ah[mt]  = *(const bf16x8*)(lA_h + (mt * 8 + ks) * 512);
            al2[mt] = *(const bf16x8*)(lA_l + (mt * 8 + ks) * 512);
        }
#pragma unroll
        for (int nt = 0; nt < 4; ++nt) {
            bf16x8 bh = *(const bf16x8*)(pB_h + (nt * 8 + ks) * 512);
            bf16x8 bl = *(const bf16x8*)(pB_l + (nt * 8 + ks) * 512);
#pragma unroll
            for (int mt = 0; mt < 3; ++mt) {
                acc[mt][nt] = __builtin_amdgcn_mfma_f32_16x16x32_bf16(ah[mt], bh, acc[mt][nt], 0, 0, 0);
                acc[mt][nt] = __builtin_amdgcn_mfma_f32_16x16x32_bf16(ah[mt], bl, acc[mt][nt], 0, 0, 0);
                acc[mt][nt] = __builtin_amdgcn_mfma_f32_16x16x32_bf16(al2[mt], bh, acc[mt][nt], 0, 0, 0);
            }
        }
    }
    __syncthreads();   // all waves done reading lsA

    // score-thread mapping: t = i*16 + ch (ch = 16-channel chunk)
    int sc_i  = t >> 4;
    int sc_ch = t & 15;
    int sc_hh = sc_ch >> 2;
    bool sc_act = (t < 368);
    int sb0 = SWZ4(4 * sc_ch + 0) * 4;
    int sb1 = SWZ4(4 * sc_ch + 1) * 4;
    int sb2 = SWZ4(4 * sc_ch + 2) * 4;
    int sb3 = SWZ4(4 * sc_ch + 3) * 4;

    // ---- per-frame attention ----
    for (int f = 0; f < 2; ++f) {
        // scatter this frame's rows from acc -> swizzled sl/sro
#pragma unroll
        for (int mt = 0; mt < 3; ++mt) {
            int rbase = mt * 16 + (l >> 4) * 4;
#pragma unroll
            for (int nt = 0; nt < 4; ++nt) {
                int col = w * 64 + nt * 16 + (l & 15);
                float* dst = (col < 256) ? sl : sro;
                int cc = col & 255;
                int coff = SWZ4(cc >> 2) * 4 + (cc & 3);
#pragma unroll
                for (int r2 = 0; r2 < 4; ++r2) {
                    int i = rbase + r2 - f * PP;
                    if (0 <= i && i < PP) dst[i * 260 + coff] = acc[mt][nt][r2];
                }
            }
        }
        __syncthreads();

        // dl/dr precompute: 184 threads, (node, head, l/r) full-64 dots (all LDS)
        if (t < 184) {
            int n = t >> 3, h = (t >> 1) & 3, which = t & 1;
            const float* base = (which ? sro : sl) + n * 260;
            float d = 0.f;
#pragma unroll
            for (int m = 0; m < 16; ++m) {
                int sb = SWZ4(h * 16 + m) * 4;
                float4 xv = *(const float4*)(base + sb);
                float4 av = *(const float4*)(satt + sb);
                d = fmaf(xv.x, av.x, d);
                d = fmaf(xv.y, av.y, d);
                d = fmaf(xv.z, av.z, d);
                d = fmaf(xv.w, av.w, d);
            }
            dldr[which * 92 + n * 4 + h] = d;
        }
        __syncthreads();

        // scores: p_abs = sum a_k |l+r|; score = 0.6(dl+dr) + 0.4 p_abs
        if (sc_act) {
            float4 av0 = *(const float4*)(satt + sb0);
            float4 av1 = *(const float4*)(satt + sb1);
            float4 av2 = *(const float4*)(satt + sb2);
            float4 av3 = *(const float4*)(satt + sb3);
            const float* srp = sro + sc_i * 260;
            float4 rv0 = *(const float4*)(srp + sb0);
            float4 rv1 = *(const float4*)(srp + sb1);
            float4 rv2 = *(const float4*)(srp + sb2);
            float4 rv3 = *(const float4*)(srp + sb3);
            float dr_i = dldr[92 + sc_i * 4 + sc_hh];
            for (int j = 0; j < PP; ++j) {
                const float* slp = sl + j * 260;
                float4 l0 = *(const float4*)(slp + sb0);
                float4 l1 = *(const float4*)(slp + sb1);
                float4 l2 = *(const float4*)(slp + sb2);
                float4 l3 = *(const float4*)(slp + sb3);
                float p = 0.f, v;
                v = l0.x + rv0.x; p = fmaf(av0.x, fabsf(v), p);
                v = l0.y + rv0.y; p = fmaf(av0.y, fabsf(v), p);
                v = l0.z + rv0.z; p = fmaf(av0.z, fabsf(v), p);
                v = l0.w + rv0.w; p = fmaf(av0.w, fabsf(v), p);
                v = l1.x + rv1.x; p = fmaf(av1.x, fabsf(v), p);
                v = l1.y + rv1.y; p = fmaf(av1.y, fabsf(v), p);
                v = l1.z + rv1.z; p = fmaf(av1.z, fabsf(v), p);
                v = l1.w + rv1.w; p = fmaf(av1.w, fabsf(v), p);
                v = l2.x + rv2.x; p = fmaf(av2.x, fabsf(v), p);
                v = l2.y + rv2.y; p = fmaf(av2.y, fabsf(v), p);
                v = l2.z + rv2.z; p = fmaf(av2.z, fabsf(v), p);
                v = l2.w + rv2.w; p = fmaf(av2.w, fabsf(v), p);
                v = l3.x + rv3.x; p = fmaf(av3.x, fabsf(v), p);
                v = l3.y + rv3.y; p = fmaf(av3.y, fabsf(v), p);
                v = l3.z + rv3.z; p = fmaf(av3.z, fabsf(v), p);
                v = l3.w + rv3.w; p = fmaf(av3.w, fabsf(v), p);
                p += __shfl_xor(p, 1, 64);
                p += __shfl_xor(p, 2, 64);
                if ((t & 3) == 0) {
                    float lin = dldr[j * 4 + sc_hh] + dr_i;
                    S[(sc_i * PP + j) * 4 + sc_hh] =
                        (j == sc_i) ? -1e30f : fmaf(0.4f, p, 0.6f * lin);
                }
            }
        }
        __syncthreads();

        // parallel softmax: 368 threads = (i, head, quad), shfl_xor reduce
        if (t < 368) {
            int i = t >> 4, hh = (t >> 2) & 3, q = t & 3;
            float m = -1e30f;
            for (int j = q; j < PP; j += 4)
                m = fmaxf(m, S[(i * PP + j) * 4 + hh]);
            m = fmaxf(m, __shfl_xor(m, 1, 64));
            m = fmaxf(m, __shfl_xor(m, 2, 64));
            float s = 0.f;
            for (int j = q; j < PP; j += 4)
                s += __expf(S[(i * PP + j) * 4 + hh] - m);
            s += __shfl_xor(s, 1, 64);
            s += __shfl_xor(s, 2, 64);
            float inv = 1.f / s;
            for (int j = q; j < PP; j += 4) {
                float* p = S + (i * PP + j) * 4 + hh;
                *p = __expf(*p - m) * inv;
            }
        }
        __syncthreads();

        // aggregate (pure LDS): outv[i][c] = sum_j alpha * hl[j][c]  (plain layout)
        {
            int c = t & 255, ip = t >> 8, hh = c >> 6;
            int coff = SWZ4(c >> 2) * 4 + (c & 3);
            float slc[PP];
#pragma unroll
            for (int j = 0; j < PP; ++j) slc[j] = sl[j * 260 + coff];
            for (int i = ip; i < PP; i += 2) {
                float accv = 0.f;
#pragma unroll
                for (int j = 0; j < PP; ++j)
                    accv = fmaf(S[(i * PP + j) * 4 + hh], slc[j], accv);
                sro[i * 260 + c] = accv;
            }
        }
        __syncthreads();

        // coalesced writeback: residual + elu + bf16 hi/lo split, 16B loads/stores
#pragma unroll
        for (int uu3 = 0; uu3 < 3; ++uu3) {
            int u = t + uu3 * 512;
            int lane = u & 63, msk = u >> 6;
            int r = ((msk >> 3) << 4) + (lane & 15);
            int i = r - f * PP;
            if (0 <= i && i < PP) {
                int kk = (msk & 7) * 32 + ((lane >> 4) << 3);
                const float* ovp = sro + i * 260 + kk;
                float4 o0 = *(const float4*)(ovp);
                float4 o1 = *(const float4*)(ovp + 4);
                bf16x8 oh = *(const bf16x8*)(Ah + pb + (size_t)u * 8);
                bf16x8 ol = *(const bf16x8*)(Al + pb + (size_t)u * 8);
                float ov0 = o0.x, ov1 = o0.y, ov2 = o0.z, ov3 = o0.w;
                float ov4 = o1.x, ov5 = o1.y, ov6 = o1.z, ov7 = o1.w;
                bf16x8 hv, lv;
#pragma unroll
                for (int e = 0; e < 8; ++e) {
                    float ov = (e == 0) ? ov0 : (e == 1) ? ov1 : (e == 2) ? ov2 :
                               (e == 3) ? ov3 : (e == 4) ? ov4 : (e == 5) ? ov5 :
                               (e == 6) ? ov6 : ov7;
                    float prev = bf2f(oh[e]) + bf2f(ol[e]);
                    float res = ov + prev;
                    float o = (res > 0.f) ? res : (__expf(res) - 1.f);
                    short hi = f2bf_rne(o);
                    hv[e] = hi;
                    lv[e] = f2bf_rne(o - bf2f(hi));
                    if (g) sro[i * 260 + kk + e] = o;   // final value for gsum pass
                }
                *(bf16x8*)(Ah + pb + (size_t)u * 8) = hv;
                *(bf16x8*)(Al + pb + (size_t)u * 8) = lv;
            }
        }
        __syncthreads();

        if (g) {   // uniform branch (kernel arg)
            {
                int c = t & 255, half = t >> 8;
                float s = 0.f;
                int i0 = half * 12, i1 = half ? PP : 12;
                for (int i = i0; i < i1; ++i) s += sro[i * 260 + c];
                gsum[half * 256 + c] = s;
            }
            __syncthreads();
            if (t < DD)
                g[(size_t)(pair * 2 + f) * DD + t] =
                    (gsum[t] + gsum[256 + t]) * (1.0f / 23.0f);
        }
    }
}

// ---------------- head: 4 graphs per block ----------------
__global__ __launch_bounds__(256) void k_head(const float* __restrict__ g,
    const float* __restrict__ Wr1, const float* __restrict__ br1,
    const float* __restrict__ Wr2, const float* __restrict__ br2,
    const float* __restrict__ Ws1, const float* __restrict__ bs1,
    const float* __restrict__ Ws2, const float* __restrict__ bs2,
    const float* __restrict__ EB, float* __restrict__ out)
{
    __shared__ float gs[4][DD], t1s[4][DD], gtop[4][DD];
    __shared__ float logits[4][CC], probs[4][CC];
    __shared__ float red[4][4];   // [wave][gg]
    int b0 = blockIdx.x * 4;
    int t = threadIdx.x;
    for (int idx = t; idx < 4 * DD; idx += 256)
        gs[idx >> 8][idx & 255] = g[(size_t)b0 * DD + idx];
    __syncthreads();

    float a1[4] = {0.f, 0.f, 0.f, 0.f}, a2[4] = {0.f, 0.f, 0.f, 0.f};
    for (int k = 0; k < DD; k += 2) {
        float w1a = Wr1[k * DD + t], w1b = Wr1[(k + 1) * DD + t];
        float w2a = Ws1[k * DD + t], w2b = Ws1[(k + 1) * DD + t];
#pragma unroll
        for (int gg = 0; gg < 4; ++gg) {
            float2 gv = *(const float2*)&gs[gg][k];
            a1[gg] = fmaf(gv.x, w1a, a1[gg]);
            a1[gg] = fmaf(gv.y, w1b, a1[gg]);
            a2[gg] = fmaf(gv.x, w2a, a2[gg]);
            a2[gg] = fmaf(gv.y, w2b, a2[gg]);
        }
    }
#pragma unroll
    for (int gg = 0; gg < 4; ++gg) {
        t1s[gg][t] = fmaxf(a1[gg] + br1[t], 0.f);
        gtop[gg][t] = a2[gg] + bs1[t];
    }
    __syncthreads();

    if (t < 4 * CC) {
        int gg = t / CC, c = t - gg * CC;
        float acc = br2[c];
        for (int d = 0; d < DD; ++d) acc = fmaf(t1s[gg][d], Wr2[d * CC + c], acc);
        logits[gg][c] = acc;
    }
    __syncthreads();
    if (t < 4 * CC) {
        int gg = t / CC, c = t - gg * CC;
        float m = -1e30f;
        for (int cc = 0; cc < CC; ++cc) m = fmaxf(m, logits[gg][cc]);
        float s = 0.f;
        for (int cc = 0; cc < CC; ++cc) s += __expf(logits[gg][cc] - m);
        probs[gg][c] = __expf(logits[gg][c] - m) / s;
    }
    __syncthreads();

    float wd = Ws2[t];
    float sacc[4];
#pragma unroll
    for (int gg = 0; gg < 4; ++gg) {
        float gt = gtop[gg][t];
        float acc = 0.f;
#pragma unroll
        for (int c = 0; c < CC; ++c)
            acc = fmaf(probs[gg][c], fmaxf(gt + EB[c * DD + t], 0.f), acc);
        sacc[gg] = acc * wd;
    }
#pragma unroll
    for (int gg = 0; gg < 4; ++gg) {
        float v = sacc[gg];
#pragma unroll
        for (int off = 32; off > 0; off >>= 1) v += __shfl_down(v, off, 64);
        if ((t & 63) == 0) red[t >> 6][gg] = v;
    }
    __syncthreads();
    if (t < 4)
        out[b0 + t] = red[0][t] + red[1][t] + red[2][t] + red[3][t] + bs2[0];
}

extern "C" void kernel_launch(void* const* d_in, const int* in_sizes, int n_in,
                              void* d_out, int out_size, void* d_ws, size_t ws_size,
                              hipStream_t stream)
{
    const float* x     = (const float*)d_in[0];
    const float* Win   = (const float*)d_in[3];
    const float* bin   = (const float*)d_in[4];
    const float* Wl    = (const float*)d_in[5];
    const float* Wr    = (const float*)d_in[6];
    const float* att   = (const float*)d_in[7];
    const float* Wr1   = (const float*)d_in[8];
    const float* br1   = (const float*)d_in[9];
    const float* Wr2   = (const float*)d_in[10];
    const float* br2   = (const float*)d_in[11];
    const float* Erecv = (const float*)d_in[12];
    const float* Ws1   = (const float*)d_in[13];
    const float* bs1   = (const float*)d_in[14];
    const float* Ws2   = (const float*)d_in[15];
    const float* bs2   = (const float*)d_in[16];
    float* out = (float*)d_out;

    short* Ah = (short*)d_ws;                       // [512][12288]
    short* Al = Ah + (size_t)NPAIR * APAIR;
    short* Bh = Al + (size_t)NPAIR * APAIR;         // [3][32][4096]
    short* Bl = Bh + (size_t)3 * 131072;
    float* g  = (float*)(Bl + (size_t)3 * 131072);  // [B][DD]
    float* EB = g + (size_t)BBATCH * DD;            // [CC][DD]

    k_prep<<<dim3(96 + CC), dim3(256), 0, stream>>>(Wl, Wr, Erecv, Ws1, Bh, Bl, EB);
    k_in_proj<<<dim3(BBATCH), dim3(256), 0, stream>>>(x, Win, bin, Ah, Al);

    for (int l = 0; l < 3; ++l) {
        k_layer<<<dim3(NPAIR), dim3(512), 0, stream>>>(Ah, Al,
            Bh + (size_t)l * 131072, Bl + (size_t)l * 131072,
            att + (size_t)l * DD, (l == 2) ? g : nullptr);
    }

    k_head<<<dim3(256), dim3(256), 0, stream>>>(g, Wr1, br1, Wr2, br2,
                                                Ws1, bs1, Ws2, bs2, EB, out);
}

// Round 10
// 228.177 us; speedup vs baseline: 1.1913x; 1.1913x over previous
//
#include <hip/hip_runtime.h>

#define BBATCH 1024
#define NPAIR 512
#define PP 23      // nodes per frame
#define FF 14
#define DD 256
#define CC 23

// ---- LDS layout (bytes) for k_fused ----
#define HS_OFF    0        // hstate [46][260] f32 = 47840, persistent
#define SL_OFF    47840    // [23][260] f32 (phase: attention)
#define SRO_OFF   71760    // [23][260] f32 (phase: attention)
#define S_OFF     95680    // [23][23][4] f32 = 8464 -> ends 104144
#define FRAGH_OFF 47840    // 12288 shorts = 24576 B (phase: GEMM; overlaps sl)
#define FRAGL_OFF 72416    // 12288 shorts -> ends 96992 (overlaps sro + S head)
#define XS_OFF    96992    // 644 f32 = 2576 B (phase: in_proj only)
#define DLDR_OFF  104144   // 184 f32 = 736
#define SATT_OFF  104880   // 256 f32 = 1024
#define SMEM_SZ   105904

// 16B-block swizzle within a 256-float row (64 blocks): involution
#define SWZ4(b) ((b) ^ (((b) >> 3) & 7))

typedef __attribute__((ext_vector_type(8))) short bf16x8;
typedef __attribute__((ext_vector_type(4))) float f32x4;

__device__ __forceinline__ short f2bf_rne(float v) {
    unsigned u = __float_as_uint(v);
    unsigned r = (u + 0x7FFFu + ((u >> 16) & 1u)) >> 16;
    return (short)(unsigned short)r;
}
__device__ __forceinline__ float bf2f(short s) {
    return __uint_as_float(((unsigned)(unsigned short)s) << 16);
}

// ---------------- weight prep (blocks 0..95) + EB (blocks 96..118) ----------------
__global__ __launch_bounds__(256) void k_prep(const float* __restrict__ Wl,
    const float* __restrict__ Wr, const float* __restrict__ E,
    const float* __restrict__ Ws1, short* __restrict__ Bh, short* __restrict__ Bl,
    float* __restrict__ EB)
{
    __shared__ float ws[DD][16];
    int t = threadIdx.x;
    if (blockIdx.x < 96) {
        int bid = blockIdx.x;            // l*32 + ntile
        int ll = bid >> 5, ntile = bid & 31;
        int n0 = ntile * 16;
        const float* W = (n0 < 256) ? (Wl + (size_t)ll * 65536) : (Wr + (size_t)ll * 65536);
        int c0 = n0 & 255;
        for (int kk = t >> 4; kk < DD; kk += 16)
            ws[kk][t & 15] = W[(size_t)kk * 256 + c0 + (t & 15)];
        __syncthreads();
        size_t base = (size_t)bid * 4096;
        for (int idx = t; idx < 4096; idx += 256) {
            int ks = idx >> 9;
            int lane = (idx >> 3) & 63;
            int e = idx & 7;
            int col = lane & 15;
            int k = ks * 32 + ((lane >> 4) << 3) + e;
            float v = ws[k][col];
            short hi = f2bf_rne(v);
            Bh[base + idx] = hi;
            Bl[base + idx] = f2bf_rne(v - bf2f(hi));
        }
    } else {
        int c = blockIdx.x - 96;
        float acc = 0.f;
        for (int k = 0; k < DD; ++k)
            acc = fmaf(E[c * DD + k], Ws1[(DD + k) * DD + t], acc);
        EB[c * DD + t] = acc;
    }
}

// ---------------- fully fused: in_proj + 3 GATv2 layers + readout ----------------
__global__ __launch_bounds__(512, 2) void k_fused(
    const float* __restrict__ x, const float* __restrict__ Win,
    const float* __restrict__ bin, const short* __restrict__ Bh,
    const short* __restrict__ Bl, const float* __restrict__ att,
    float* __restrict__ g)
{
    __shared__ __align__(16) char smem[SMEM_SZ];
    float* hstate = (float*)(smem + HS_OFF);    // [46][260] f32, persistent
    float* sl     = (float*)(smem + SL_OFF);    // swizzled hl
    float* sro    = (float*)(smem + SRO_OFF);   // swizzled hr
    float* S      = (float*)(smem + S_OFF);
    short* fragH  = (short*)(smem + FRAGH_OFF); // packed bf16 hi
    short* fragL  = (short*)(smem + FRAGL_OFF); // packed bf16 lo
    float* xs     = (float*)(smem + XS_OFF);    // [46][14]
    float* dldr   = (float*)(smem + DLDR_OFF);
    float* satt   = (float*)(smem + SATT_OFF);

    int t = threadIdx.x;
    int pair = blockIdx.x;

    // ---- stage x for this pair ----
    for (int idx = t; idx < 46 * FF; idx += 512)
        xs[idx] = x[(size_t)pair * 46 * FF + idx];
    __syncthreads();

    // ---- in_proj: h0 = x@Win + bin -> hstate (f32) + fragH/fragL ----
    {
        int c2 = (t & 127) * 2;
        int rp = t >> 7;
        float w0[FF], w1[FF];
#pragma unroll
        for (int f = 0; f < FF; ++f) {
            float2 wv = *(const float2*)&Win[f * DD + c2];
            w0[f] = wv.x; w1[f] = wv.y;
        }
        float2 bb = *(const float2*)&bin[c2];
        for (int r = rp; r < 48; r += 4) {
            float h0 = 0.f, h1 = 0.f;
            if (r < 46) {
                h0 = bb.x; h1 = bb.y;
#pragma unroll
                for (int f = 0; f < FF; ++f) {
                    float xv = xs[r * FF + f];
                    h0 = fmaf(xv, w0[f], h0);
                    h1 = fmaf(xv, w1[f], h1);
                }
                *(float2*)&hstate[r * 260 + c2] = make_float2(h0, h1);
            }
            int off = ((r >> 4) * 8 + (c2 >> 5)) * 512 +
                      ((r & 15) + (((c2 & 31) >> 3) << 4)) * 8 + (c2 & 7);
            short hi0 = f2bf_rne(h0), hi1 = f2bf_rne(h1);
            short lo0 = f2bf_rne(h0 - bf2f(hi0)), lo1 = f2bf_rne(h1 - bf2f(hi1));
            *(unsigned*)(&fragH[off]) =
                (unsigned)(unsigned short)hi0 | ((unsigned)(unsigned short)hi1 << 16);
            *(unsigned*)(&fragL[off]) =
                (unsigned)(unsigned short)lo0 | ((unsigned)(unsigned short)lo1 << 16);
        }
    }

    int ln = t & 63, w = t >> 6;

    // score-thread mapping constants
    int sc_i  = t >> 4;
    int sc_ch = t & 15;
    int sc_hh = sc_ch >> 2;
    bool sc_act = (t < 368);
    int sb0 = SWZ4(4 * sc_ch + 0) * 4;
    int sb1 = SWZ4(4 * sc_ch + 1) * 4;
    int sb2 = SWZ4(4 * sc_ch + 2) * 4;
    int sb3 = SWZ4(4 * sc_ch + 3) * 4;

    for (int layer = 0; layer < 3; ++layer) {
        if (t < DD) satt[SWZ4(t >> 2) * 4 + (t & 3)] = att[layer * DD + t];

        if (layer > 0) {
            // convert hstate -> fragH/fragL (packed bf16 hi/lo)
            int c2 = (t & 127) * 2;
            int rp = t >> 7;
            for (int r = rp; r < 48; r += 4) {
                float h0 = 0.f, h1 = 0.f;
                if (r < 46) {
                    float2 hv = *(const float2*)&hstate[r * 260 + c2];
                    h0 = hv.x; h1 = hv.y;
                }
                int off = ((r >> 4) * 8 + (c2 >> 5)) * 512 +
                          ((r & 15) + (((c2 & 31) >> 3) << 4)) * 8 + (c2 & 7);
                short hi0 = f2bf_rne(h0), hi1 = f2bf_rne(h1);
                short lo0 = f2bf_rne(h0 - bf2f(hi0)), lo1 = f2bf_rne(h1 - bf2f(hi1));
                *(unsigned*)(&fragH[off]) =
                    (unsigned)(unsigned short)hi0 | ((unsigned)(unsigned short)hi1 << 16);
                *(unsigned*)(&fragL[off]) =
                    (unsigned)(unsigned short)lo0 | ((unsigned)(unsigned short)lo1 << 16);
            }
        }
        __syncthreads();   // frags + satt ready

        // ---- GEMM: M=46(+2 pad), N=512, K=256, bf16 hi/lo 3-term ----
        const short* pB_h = Bh + (size_t)layer * 131072 + (size_t)(w * 4) * 4096 + ln * 8;
        const short* pB_l = Bl + (size_t)layer * 131072 + (size_t)(w * 4) * 4096 + ln * 8;
        const short* lA_h = fragH + ln * 8;
        const short* lA_l = fragL + ln * 8;

        f32x4 acc[3][4];
#pragma unroll
        for (int mt = 0; mt < 3; ++mt)
#pragma unroll
            for (int nt = 0; nt < 4; ++nt) acc[mt][nt] = (f32x4)0.0f;

#pragma unroll
        for (int ks = 0; ks < 8; ++ks) {
            bf16x8 ah[3], al2[3];
#pragma unroll
            for (int mt = 0; mt < 3; ++mt) {
                ah[mt]  = *(const bf16x8*)(lA_h + (mt * 8 + ks) * 512);
                al2[mt] = *(const bf16x8*)(lA_l + (mt * 8 + ks) * 512);
            }
#pragma unroll
            for (int nt = 0; nt < 4; ++nt) {
                bf16x8 bh = *(const bf16x8*)(pB_h + (nt * 8 + ks) * 512);
                bf16x8 bl = *(const bf16x8*)(pB_l + (nt * 8 + ks) * 512);
#pragma unroll
                for (int mt = 0; mt < 3; ++mt) {
                    acc[mt][nt] = __builtin_amdgcn_mfma_f32_16x16x32_bf16(ah[mt], bh, acc[mt][nt], 0, 0, 0);
                    acc[mt][nt] = __builtin_amdgcn_mfma_f32_16x16x32_bf16(ah[mt], bl, acc[mt][nt], 0, 0, 0);
                    acc[mt][nt] = __builtin_amdgcn_mfma_f32_16x16x32_bf16(al2[mt], bh, acc[mt][nt], 0, 0, 0);
                }
            }
        }
        __syncthreads();   // frags dead; sl/sro/S region reusable

        // ---- per-frame attention ----
        for (int f = 0; f < 2; ++f) {
            // scatter this frame's rows from acc -> swizzled sl/sro
#pragma unroll
            for (int mt = 0; mt < 3; ++mt) {
                int rbase = mt * 16 + (ln >> 4) * 4;
#pragma unroll
                for (int nt = 0; nt < 4; ++nt) {
                    int col = w * 64 + nt * 16 + (ln & 15);
                    float* dst = (col < 256) ? sl : sro;
                    int cc = col & 255;
                    int coff = SWZ4(cc >> 2) * 4 + (cc & 3);
#pragma unroll
                    for (int r2 = 0; r2 < 4; ++r2) {
                        int i = rbase + r2 - f * PP;
                        if (0 <= i && i < PP) dst[i * 260 + coff] = acc[mt][nt][r2];
                    }
                }
            }
            __syncthreads();

            // dl/dr precompute: 184 threads, (node, head, l/r) full-64 dots
            if (t < 184) {
                int n = t >> 3, h = (t >> 1) & 3, which = t & 1;
                const float* base = (which ? sro : sl) + n * 260;
                float d = 0.f;
#pragma unroll
                for (int m = 0; m < 16; ++m) {
                    int sb = SWZ4(h * 16 + m) * 4;
                    float4 xv = *(const float4*)(base + sb);
                    float4 av = *(const float4*)(satt + sb);
                    d = fmaf(xv.x, av.x, d);
                    d = fmaf(xv.y, av.y, d);
                    d = fmaf(xv.z, av.z, d);
                    d = fmaf(xv.w, av.w, d);
                }
                dldr[which * 92 + n * 4 + h] = d;
            }
            __syncthreads();

            // scores: p_abs = sum a_k |l+r|; score = 0.6(dl+dr) + 0.4 p_abs
            if (sc_act) {
                float4 av0 = *(const float4*)(satt + sb0);
                float4 av1 = *(const float4*)(satt + sb1);
                float4 av2 = *(const float4*)(satt + sb2);
                float4 av3 = *(const float4*)(satt + sb3);
                const float* srp = sro + sc_i * 260;
                float4 rv0 = *(const float4*)(srp + sb0);
                float4 rv1 = *(const float4*)(srp + sb1);
                float4 rv2 = *(const float4*)(srp + sb2);
                float4 rv3 = *(const float4*)(srp + sb3);
                float dr_i = dldr[92 + sc_i * 4 + sc_hh];
                for (int j = 0; j < PP; ++j) {
                    const float* slp = sl + j * 260;
                    float4 l0 = *(const float4*)(slp + sb0);
                    float4 l1 = *(const float4*)(slp + sb1);
                    float4 l2 = *(const float4*)(slp + sb2);
                    float4 l3 = *(const float4*)(slp + sb3);
                    float p = 0.f, v;
                    v = l0.x + rv0.x; p = fmaf(av0.x, fabsf(v), p);
                    v = l0.y + rv0.y; p = fmaf(av0.y, fabsf(v), p);
                    v = l0.z + rv0.z; p = fmaf(av0.z, fabsf(v), p);
                    v = l0.w + rv0.w; p = fmaf(av0.w, fabsf(v), p);
                    v = l1.x + rv1.x; p = fmaf(av1.x, fabsf(v), p);
                    v = l1.y + rv1.y; p = fmaf(av1.y, fabsf(v), p);
                    v = l1.z + rv1.z; p = fmaf(av1.z, fabsf(v), p);
                    v = l1.w + rv1.w; p = fmaf(av1.w, fabsf(v), p);
                    v = l2.x + rv2.x; p = fmaf(av2.x, fabsf(v), p);
                    v = l2.y + rv2.y; p = fmaf(av2.y, fabsf(v), p);
                    v = l2.z + rv2.z; p = fmaf(av2.z, fabsf(v), p);
                    v = l2.w + rv2.w; p = fmaf(av2.w, fabsf(v), p);
                    v = l3.x + rv3.x; p = fmaf(av3.x, fabsf(v), p);
                    v = l3.y + rv3.y; p = fmaf(av3.y, fabsf(v), p);
                    v = l3.z + rv3.z; p = fmaf(av3.z, fabsf(v), p);
                    v = l3.w + rv3.w; p = fmaf(av3.w, fabsf(v), p);
                    p += __shfl_xor(p, 1, 64);
                    p += __shfl_xor(p, 2, 64);
                    if ((t & 3) == 0) {
                        float lin = dldr[j * 4 + sc_hh] + dr_i;
                        S[(sc_i * PP + j) * 4 + sc_hh] =
                            (j == sc_i) ? -1e30f : fmaf(0.4f, p, 0.6f * lin);
                    }
                }
            }
            __syncthreads();

            // parallel softmax: 368 threads = (i, head, quad)
            if (t < 368) {
                int i = t >> 4, hh = (t >> 2) & 3, q = t & 3;
                float m = -1e30f;
                for (int j = q; j < PP; j += 4)
                    m = fmaxf(m, S[(i * PP + j) * 4 + hh]);
                m = fmaxf(m, __shfl_xor(m, 1, 64));
                m = fmaxf(m, __shfl_xor(m, 2, 64));
                float s = 0.f;
                for (int j = q; j < PP; j += 4)
                    s += __expf(S[(i * PP + j) * 4 + hh] - m);
                s += __shfl_xor(s, 1, 64);
                s += __shfl_xor(s, 2, 64);
                float inv = 1.f / s;
                for (int j = q; j < PP; j += 4) {
                    float* p = S + (i * PP + j) * 4 + hh;
                    *p = __expf(*p - m) * inv;
                }
            }
            __syncthreads();

            // aggregate + residual(f32) + elu -> hstate (pure LDS)
            {
                int c = t & 255, ip = t >> 8, hh = c >> 6;
                int coff = SWZ4(c >> 2) * 4 + (c & 3);
                float slc[PP];
#pragma unroll
                for (int j = 0; j < PP; ++j) slc[j] = sl[j * 260 + coff];
                for (int i = ip; i < PP; i += 2) {
                    float accv = 0.f;
#pragma unroll
                    for (int j = 0; j < PP; ++j)
                        accv = fmaf(S[(i * PP + j) * 4 + hh], slc[j], accv);
                    int r = f * PP + i;
                    float res = accv + hstate[r * 260 + c];
                    hstate[r * 260 + c] = (res > 0.f) ? res : (__expf(res) - 1.f);
                }
            }
            __syncthreads();   // sl/sro/S free; hstate updated
        }
    }

    // ---- readout: g[frame] = mean_i hstate ----
    {
        int f = t >> 8, c = t & 255;
        float s = 0.f;
#pragma unroll
        for (int i = 0; i < PP; ++i) s += hstate[(f * PP + i) * 260 + c];
        g[(size_t)(pair * 2 + f) * DD + c] = s * (1.0f / 23.0f);
    }
}

// ---------------- head: 4 graphs per block ----------------
__global__ __launch_bounds__(256) void k_head(const float* __restrict__ g,
    const float* __restrict__ Wr1, const float* __restrict__ br1,
    const float* __restrict__ Wr2, const float* __restrict__ br2,
    const float* __restrict__ Ws1, const float* __restrict__ bs1,
    const float* __restrict__ Ws2, const float* __restrict__ bs2,
    const float* __restrict__ EB, float* __restrict__ out)
{
    __shared__ float gs[4][DD], t1s[4][DD], gtop[4][DD];
    __shared__ float logits[4][CC], probs[4][CC];
    __shared__ float red[4][4];   // [wave][gg]
    int b0 = blockIdx.x * 4;
    int t = threadIdx.x;
    for (int idx = t; idx < 4 * DD; idx += 256)
        gs[idx >> 8][idx & 255] = g[(size_t)b0 * DD + idx];
    __syncthreads();

    float a1[4] = {0.f, 0.f, 0.f, 0.f}, a2[4] = {0.f, 0.f, 0.f, 0.f};
    for (int k = 0; k < DD; k += 2) {
        float w1a = Wr1[k * DD + t], w1b = Wr1[(k + 1) * DD + t];
        float w2a = Ws1[k * DD + t], w2b = Ws1[(k + 1) * DD + t];
#pragma unroll
        for (int gg = 0; gg < 4; ++gg) {
            float2 gv = *(const float2*)&gs[gg][k];
            a1[gg] = fmaf(gv.x, w1a, a1[gg]);
            a1[gg] = fmaf(gv.y, w1b, a1[gg]);
            a2[gg] = fmaf(gv.x, w2a, a2[gg]);
            a2[gg] = fmaf(gv.y, w2b, a2[gg]);
        }
    }
#pragma unroll
    for (int gg = 0; gg < 4; ++gg) {
        t1s[gg][t] = fmaxf(a1[gg] + br1[t], 0.f);
        gtop[gg][t] = a2[gg] + bs1[t];
    }
    __syncthreads();

    if (t < 4 * CC) {
        int gg = t / CC, c = t - gg * CC;
        float acc = br2[c];
        for (int d = 0; d < DD; ++d) acc = fmaf(t1s[gg][d], Wr2[d * CC + c], acc);
        logits[gg][c] = acc;
    }
    __syncthreads();
    if (t < 4 * CC) {
        int gg = t / CC, c = t - gg * CC;
        float m = -1e30f;
        for (int cc = 0; cc < CC; ++cc) m = fmaxf(m, logits[gg][cc]);
        float s = 0.f;
        for (int cc = 0; cc < CC; ++cc) s += __expf(logits[gg][cc] - m);
        probs[gg][c] = __expf(logits[gg][c] - m) / s;
    }
    __syncthreads();

    float wd = Ws2[t];
    float sacc[4];
#pragma unroll
    for (int gg = 0; gg < 4; ++gg) {
        float gt = gtop[gg][t];
        float acc = 0.f;
#pragma unroll
        for (int c = 0; c < CC; ++c)
            acc = fmaf(probs[gg][c], fmaxf(gt + EB[c * DD + t], 0.f), acc);
        sacc[gg] = acc * wd;
    }
#pragma unroll
    for (int gg = 0; gg < 4; ++gg) {
        float v = sacc[gg];
#pragma unroll
        for (int off = 32; off > 0; off >>= 1) v += __shfl_down(v, off, 64);
        if ((t & 63) == 0) red[t >> 6][gg] = v;
    }
    __syncthreads();
    if (t < 4)
        out[b0 + t] = red[0][t] + red[1][t] + red[2][t] + red[3][t] + bs2[0];
}

extern "C" void kernel_launch(void* const* d_in, const int* in_sizes, int n_in,
                              void* d_out, int out_size, void* d_ws, size_t ws_size,
                              hipStream_t stream)
{
    const float* x     = (const float*)d_in[0];
    const float* Win   = (const float*)d_in[3];
    const float* bin   = (const float*)d_in[4];
    const float* Wl    = (const float*)d_in[5];
    const float* Wr    = (const float*)d_in[6];
    const float* att   = (const float*)d_in[7];
    const float* Wr1   = (const float*)d_in[8];
    const float* br1   = (const float*)d_in[9];
    const float* Wr2   = (const float*)d_in[10];
    const float* br2   = (const float*)d_in[11];
    const float* Erecv = (const float*)d_in[12];
    const float* Ws1   = (const float*)d_in[13];
    const float* bs1   = (const float*)d_in[14];
    const float* Ws2   = (const float*)d_in[15];
    const float* bs2   = (const float*)d_in[16];
    float* out = (float*)d_out;

    short* Bh = (short*)d_ws;                       // [3][32][4096]
    short* Bl = Bh + (size_t)3 * 131072;
    float* g  = (float*)(Bl + (size_t)3 * 131072);  // [B][DD]
    float* EB = g + (size_t)BBATCH * DD;            // [CC][DD]

    k_prep<<<dim3(96 + CC), dim3(256), 0, stream>>>(Wl, Wr, Erecv, Ws1, Bh, Bl, EB);
    k_fused<<<dim3(NPAIR), dim3(512), 0, stream>>>(x, Win, bin, Bh, Bl, att, g);
    k_head<<<dim3(256), dim3(256), 0, stream>>>(g, Wr1, br1, Wr2, br2,
                                                Ws1, bs1, Ws2, bs2, EB, out);
}

// Round 11
// 212.599 us; speedup vs baseline: 1.2786x; 1.0733x over previous
//
#include <hip/hip_runtime.h>

#define BBATCH 1024
#define NPAIR 512
#define PP 23      // nodes per frame
#define FF 14
#define DD 256
#define CC 23

// ---- LDS layout (bytes) for k_fused ----
#define HS_OFF    0        // hstate [46][260] f32 = 47840, persistent
#define SL_OFF    47840    // [23][260] f32 (phase: attention)
#define SRO_OFF   71760    // [23][260] f32 (phase: attention)
#define S_OFF     95680    // [23][23][4] f32 = 8464 -> ends 104144
#define FRAGH_OFF 47840    // 12288 shorts = 24576 B (phase: GEMM; overlaps sl)
#define FRAGL_OFF 72416    // 12288 shorts -> ends 96992 (overlaps sro + S head)
#define XS_OFF    96992    // 644 f32 = 2576 B (phase: in_proj only)
#define DLDR_OFF  104144   // 184 f32 = 736
#define SATT_OFF  104880   // 256 f32 = 1024
#define SMEM_SZ   105904

// 16B-block swizzle within a 256-float row (64 blocks): involution
#define SWZ4(b) ((b) ^ (((b) >> 3) & 7))

typedef __attribute__((ext_vector_type(8))) short bf16x8;
typedef __attribute__((ext_vector_type(4))) float f32x4;

__device__ __forceinline__ short f2bf_rne(float v) {
    unsigned u = __float_as_uint(v);
    unsigned r = (u + 0x7FFFu + ((u >> 16) & 1u)) >> 16;
    return (short)(unsigned short)r;
}
__device__ __forceinline__ float bf2f(short s) {
    return __uint_as_float(((unsigned)(unsigned short)s) << 16);
}

// ---------------- weight prep (blocks 0..95) + EB (blocks 96..118) ----------------
__global__ __launch_bounds__(256) void k_prep(const float* __restrict__ Wl,
    const float* __restrict__ Wr, const float* __restrict__ E,
    const float* __restrict__ Ws1, short* __restrict__ Bh, short* __restrict__ Bl,
    float* __restrict__ EB)
{
    __shared__ float ws[DD][16];
    int t = threadIdx.x;
    if (blockIdx.x < 96) {
        int bid = blockIdx.x;            // l*32 + ntile
        int ll = bid >> 5, ntile = bid & 31;
        int n0 = ntile * 16;
        const float* W = (n0 < 256) ? (Wl + (size_t)ll * 65536) : (Wr + (size_t)ll * 65536);
        int c0 = n0 & 255;
        for (int kk = t >> 4; kk < DD; kk += 16)
            ws[kk][t & 15] = W[(size_t)kk * 256 + c0 + (t & 15)];
        __syncthreads();
        size_t base = (size_t)bid * 4096;
        for (int idx = t; idx < 4096; idx += 256) {
            int ks = idx >> 9;
            int lane = (idx >> 3) & 63;
            int e = idx & 7;
            int col = lane & 15;
            int k = ks * 32 + ((lane >> 4) << 3) + e;
            float v = ws[k][col];
            short hi = f2bf_rne(v);
            Bh[base + idx] = hi;
            Bl[base + idx] = f2bf_rne(v - bf2f(hi));
        }
    } else {
        int c = blockIdx.x - 96;
        float acc = 0.f;
        for (int k = 0; k < DD; ++k)
            acc = fmaf(E[c * DD + k], Ws1[(DD + k) * DD + t], acc);
        EB[c * DD + t] = acc;
    }
}

// ---------------- fully fused: in_proj + 3 GATv2 layers + readout (1024 thr) ----------------
__global__ __launch_bounds__(1024, 4) void k_fused(
    const float* __restrict__ x, const float* __restrict__ Win,
    const float* __restrict__ bin, const short* __restrict__ Bh,
    const short* __restrict__ Bl, const float* __restrict__ att,
    float* __restrict__ g)
{
    __shared__ __align__(16) char smem[SMEM_SZ];
    float* hstate = (float*)(smem + HS_OFF);    // [46][260] f32, persistent
    float* sl     = (float*)(smem + SL_OFF);    // swizzled hl
    float* sro    = (float*)(smem + SRO_OFF);   // swizzled hr
    float* S      = (float*)(smem + S_OFF);
    short* fragH  = (short*)(smem + FRAGH_OFF); // packed bf16 hi
    short* fragL  = (short*)(smem + FRAGL_OFF); // packed bf16 lo
    float* xs     = (float*)(smem + XS_OFF);    // [46][14]
    float* dldr   = (float*)(smem + DLDR_OFF);
    float* satt   = (float*)(smem + SATT_OFF);

    int t = threadIdx.x;
    int pair = blockIdx.x;

    // ---- stage x for this pair ----
    for (int idx = t; idx < 46 * FF; idx += 1024)
        xs[idx] = x[(size_t)pair * 46 * FF + idx];
    __syncthreads();

    // ---- in_proj: h0 = x@Win + bin -> hstate (f32) + fragH/fragL ----
    {
        int c2 = (t & 127) * 2;
        int rp = t >> 7;          // 0..7
        float w0[FF], w1[FF];
#pragma unroll
        for (int f = 0; f < FF; ++f) {
            float2 wv = *(const float2*)&Win[f * DD + c2];
            w0[f] = wv.x; w1[f] = wv.y;
        }
        float2 bb = *(const float2*)&bin[c2];
        for (int r = rp; r < 48; r += 8) {
            float h0 = 0.f, h1 = 0.f;
            if (r < 46) {
                h0 = bb.x; h1 = bb.y;
#pragma unroll
                for (int f = 0; f < FF; ++f) {
                    float xv = xs[r * FF + f];
                    h0 = fmaf(xv, w0[f], h0);
                    h1 = fmaf(xv, w1[f], h1);
                }
                *(float2*)&hstate[r * 260 + c2] = make_float2(h0, h1);
            }
            int off = ((r >> 4) * 8 + (c2 >> 5)) * 512 +
                      ((r & 15) + (((c2 & 31) >> 3) << 4)) * 8 + (c2 & 7);
            short hi0 = f2bf_rne(h0), hi1 = f2bf_rne(h1);
            short lo0 = f2bf_rne(h0 - bf2f(hi0)), lo1 = f2bf_rne(h1 - bf2f(hi1));
            *(unsigned*)(&fragH[off]) =
                (unsigned)(unsigned short)hi0 | ((unsigned)(unsigned short)hi1 << 16);
            *(unsigned*)(&fragL[off]) =
                (unsigned)(unsigned short)lo0 | ((unsigned)(unsigned short)lo1 << 16);
        }
    }

    int ln = t & 63, w = t >> 6;   // 16 waves

    // score-thread mapping: t = i*32 + jh*16 + ch  (736 active)
    int sc_i  = t >> 5;
    int sc_jh = (t >> 4) & 1;
    int sc_ch = t & 15;
    int sc_hh = sc_ch >> 2;
    bool sc_act = (t < 736);
    int sb0 = SWZ4(4 * sc_ch + 0) * 4;
    int sb1 = SWZ4(4 * sc_ch + 1) * 4;
    int sb2 = SWZ4(4 * sc_ch + 2) * 4;
    int sb3 = SWZ4(4 * sc_ch + 3) * 4;

    for (int layer = 0; layer < 3; ++layer) {
        if (t < DD) satt[SWZ4(t >> 2) * 4 + (t & 3)] = att[layer * DD + t];

        if (layer > 0) {
            // convert hstate -> fragH/fragL (packed bf16 hi/lo)
            int c2 = (t & 127) * 2;
            int rp = t >> 7;
            for (int r = rp; r < 48; r += 8) {
                float h0 = 0.f, h1 = 0.f;
                if (r < 46) {
                    float2 hv = *(const float2*)&hstate[r * 260 + c2];
                    h0 = hv.x; h1 = hv.y;
                }
                int off = ((r >> 4) * 8 + (c2 >> 5)) * 512 +
                          ((r & 15) + (((c2 & 31) >> 3) << 4)) * 8 + (c2 & 7);
                short hi0 = f2bf_rne(h0), hi1 = f2bf_rne(h1);
                short lo0 = f2bf_rne(h0 - bf2f(hi0)), lo1 = f2bf_rne(h1 - bf2f(hi1));
                *(unsigned*)(&fragH[off]) =
                    (unsigned)(unsigned short)hi0 | ((unsigned)(unsigned short)hi1 << 16);
                *(unsigned*)(&fragL[off]) =
                    (unsigned)(unsigned short)lo0 | ((unsigned)(unsigned short)lo1 << 16);
            }
        }
        __syncthreads();   // frags + satt ready

        // ---- GEMM: 16 waves x 2 ntiles; M=46(+2 pad), N=512, K=256 ----
        const short* pB_h = Bh + (size_t)layer * 131072 + (size_t)(w * 2) * 4096 + ln * 8;
        const short* pB_l = Bl + (size_t)layer * 131072 + (size_t)(w * 2) * 4096 + ln * 8;
        const short* lA_h = fragH + ln * 8;
        const short* lA_l = fragL + ln * 8;

        f32x4 acc[3][2];
#pragma unroll
        for (int mt = 0; mt < 3; ++mt)
#pragma unroll
            for (int nt = 0; nt < 2; ++nt) acc[mt][nt] = (f32x4)0.0f;

#pragma unroll
        for (int ks = 0; ks < 8; ++ks) {
            bf16x8 ah[3], al2[3];
#pragma unroll
            for (int mt = 0; mt < 3; ++mt) {
                ah[mt]  = *(const bf16x8*)(lA_h + (mt * 8 + ks) * 512);
                al2[mt] = *(const bf16x8*)(lA_l + (mt * 8 + ks) * 512);
            }
#pragma unroll
            for (int nt = 0; nt < 2; ++nt) {
                bf16x8 bh = *(const bf16x8*)(pB_h + (nt * 8 + ks) * 512);
                bf16x8 bl = *(const bf16x8*)(pB_l + (nt * 8 + ks) * 512);
#pragma unroll
                for (int mt = 0; mt < 3; ++mt) {
                    acc[mt][nt] = __builtin_amdgcn_mfma_f32_16x16x32_bf16(ah[mt], bh, acc[mt][nt], 0, 0, 0);
                    acc[mt][nt] = __builtin_amdgcn_mfma_f32_16x16x32_bf16(ah[mt], bl, acc[mt][nt], 0, 0, 0);
                    acc[mt][nt] = __builtin_amdgcn_mfma_f32_16x16x32_bf16(al2[mt], bh, acc[mt][nt], 0, 0, 0);
                }
            }
        }
        __syncthreads();   // frags dead; sl/sro/S region reusable

        // ---- per-frame attention ----
        for (int f = 0; f < 2; ++f) {
            // scatter this frame's rows from acc -> swizzled sl/sro
#pragma unroll
            for (int mt = 0; mt < 3; ++mt) {
                int rbase = mt * 16 + (ln >> 4) * 4;
#pragma unroll
                for (int nt = 0; nt < 2; ++nt) {
                    int col = w * 32 + nt * 16 + (ln & 15);
                    float* dst = (col < 256) ? sl : sro;
                    int cc = col & 255;
                    int coff = SWZ4(cc >> 2) * 4 + (cc & 3);
#pragma unroll
                    for (int r2 = 0; r2 < 4; ++r2) {
                        int i = rbase + r2 - f * PP;
                        if (0 <= i && i < PP) dst[i * 260 + coff] = acc[mt][nt][r2];
                    }
                }
            }
            __syncthreads();

            // dl/dr precompute: 368 threads = (node, head, l/r, m-half)
            if (t < 368) {
                int u = t >> 1, half = t & 1;
                int n = u >> 3, h = (u >> 1) & 3, which = u & 1;
                const float* base = (which ? sro : sl) + n * 260;
                float d = 0.f;
#pragma unroll
                for (int m2 = 0; m2 < 8; ++m2) {
                    int m = half * 8 + m2;
                    int sb = SWZ4(h * 16 + m) * 4;
                    float4 xv = *(const float4*)(base + sb);
                    float4 av = *(const float4*)(satt + sb);
                    d = fmaf(xv.x, av.x, d);
                    d = fmaf(xv.y, av.y, d);
                    d = fmaf(xv.z, av.z, d);
                    d = fmaf(xv.w, av.w, d);
                }
                d += __shfl_xor(d, 1, 64);
                if (half == 0) dldr[which * 92 + n * 4 + h] = d;
            }
            __syncthreads();

            // scores: (i, j-parity, ch); p_abs = sum a_k |l+r|
            if (sc_act) {
                float4 av0 = *(const float4*)(satt + sb0);
                float4 av1 = *(const float4*)(satt + sb1);
                float4 av2 = *(const float4*)(satt + sb2);
                float4 av3 = *(const float4*)(satt + sb3);
                const float* srp = sro + sc_i * 260;
                float4 rv0 = *(const float4*)(srp + sb0);
                float4 rv1 = *(const float4*)(srp + sb1);
                float4 rv2 = *(const float4*)(srp + sb2);
                float4 rv3 = *(const float4*)(srp + sb3);
                float dr_i = dldr[92 + sc_i * 4 + sc_hh];
                for (int j = sc_jh; j < PP; j += 2) {
                    const float* slp = sl + j * 260;
                    float4 l0 = *(const float4*)(slp + sb0);
                    float4 l1 = *(const float4*)(slp + sb1);
                    float4 l2 = *(const float4*)(slp + sb2);
                    float4 l3 = *(const float4*)(slp + sb3);
                    float p = 0.f, v;
                    v = l0.x + rv0.x; p = fmaf(av0.x, fabsf(v), p);
                    v = l0.y + rv0.y; p = fmaf(av0.y, fabsf(v), p);
                    v = l0.z + rv0.z; p = fmaf(av0.z, fabsf(v), p);
                    v = l0.w + rv0.w; p = fmaf(av0.w, fabsf(v), p);
                    v = l1.x + rv1.x; p = fmaf(av1.x, fabsf(v), p);
                    v = l1.y + rv1.y; p = fmaf(av1.y, fabsf(v), p);
                    v = l1.z + rv1.z; p = fmaf(av1.z, fabsf(v), p);
                    v = l1.w + rv1.w; p = fmaf(av1.w, fabsf(v), p);
                    v = l2.x + rv2.x; p = fmaf(av2.x, fabsf(v), p);
                    v = l2.y + rv2.y; p = fmaf(av2.y, fabsf(v), p);
                    v = l2.z + rv2.z; p = fmaf(av2.z, fabsf(v), p);
                    v = l2.w + rv2.w; p = fmaf(av2.w, fabsf(v), p);
                    v = l3.x + rv3.x; p = fmaf(av3.x, fabsf(v), p);
                    v = l3.y + rv3.y; p = fmaf(av3.y, fabsf(v), p);
                    v = l3.z + rv3.z; p = fmaf(av3.z, fabsf(v), p);
                    v = l3.w + rv3.w; p = fmaf(av3.w, fabsf(v), p);
                    p += __shfl_xor(p, 1, 64);
                    p += __shfl_xor(p, 2, 64);
                    if ((t & 3) == 0) {
                        float lin = dldr[j * 4 + sc_hh] + dr_i;
                        S[(sc_i * PP + j) * 4 + sc_hh] =
                            (j == sc_i) ? -1e30f : fmaf(0.4f, p, 0.6f * lin);
                    }
                }
            }
            __syncthreads();

            // parallel softmax: 368 threads = (i, head, quad)
            if (t < 368) {
                int i = t >> 4, hh = (t >> 2) & 3, q = t & 3;
                float m = -1e30f;
                for (int j = q; j < PP; j += 4)
                    m = fmaxf(m, S[(i * PP + j) * 4 + hh]);
                m = fmaxf(m, __shfl_xor(m, 1, 64));
                m = fmaxf(m, __shfl_xor(m, 2, 64));
                float s = 0.f;
                for (int j = q; j < PP; j += 4)
                    s += __expf(S[(i * PP + j) * 4 + hh] - m);
                s += __shfl_xor(s, 1, 64);
                s += __shfl_xor(s, 2, 64);
                float inv = 1.f / s;
                for (int j = q; j < PP; j += 4) {
                    float* p = S + (i * PP + j) * 4 + hh;
                    *p = __expf(*p - m) * inv;
                }
            }
            __syncthreads();

            // aggregate + residual(f32) + elu -> hstate (pure LDS)
            {
                int c = t & 255, ip = t >> 8, hh = c >> 6;
                int coff = SWZ4(c >> 2) * 4 + (c & 3);
                float slc[PP];
#pragma unroll
                for (int j = 0; j < PP; ++j) slc[j] = sl[j * 260 + coff];
                for (int i = ip; i < PP; i += 4) {
                    float accv = 0.f;
#pragma unroll
                    for (int j = 0; j < PP; ++j)
                        accv = fmaf(S[(i * PP + j) * 4 + hh], slc[j], accv);
                    int r = f * PP + i;
                    float res = accv + hstate[r * 260 + c];
                    hstate[r * 260 + c] = (res > 0.f) ? res : (__expf(res) - 1.f);
                }
            }
            __syncthreads();   // sl/sro/S free; hstate updated
        }
    }

    // ---- readout: g[frame] = mean_i hstate ----
    if (t < 512) {
        int f = t >> 8, c = t & 255;
        float s = 0.f;
#pragma unroll
        for (int i = 0; i < PP; ++i) s += hstate[(f * PP + i) * 260 + c];
        g[(size_t)(pair * 2 + f) * DD + c] = s * (1.0f / 23.0f);
    }
}

// ---------------- head: 4 graphs per block ----------------
__global__ __launch_bounds__(256) void k_head(const float* __restrict__ g,
    const float* __restrict__ Wr1, const float* __restrict__ br1,
    const float* __restrict__ Wr2, const float* __restrict__ br2,
    const float* __restrict__ Ws1, const float* __restrict__ bs1,
    const float* __restrict__ Ws2, const float* __restrict__ bs2,
    const float* __restrict__ EB, float* __restrict__ out)
{
    __shared__ float gs[4][DD], t1s[4][DD], gtop[4][DD];
    __shared__ float logits[4][CC], probs[4][CC];
    __shared__ float red[4][4];   // [wave][gg]
    int b0 = blockIdx.x * 4;
    int t = threadIdx.x;
    for (int idx = t; idx < 4 * DD; idx += 256)
        gs[idx >> 8][idx & 255] = g[(size_t)b0 * DD + idx];
    __syncthreads();

    float a1[4] = {0.f, 0.f, 0.f, 0.f}, a2[4] = {0.f, 0.f, 0.f, 0.f};
    for (int k = 0; k < DD; k += 2) {
        float w1a = Wr1[k * DD + t], w1b = Wr1[(k + 1) * DD + t];
        float w2a = Ws1[k * DD + t], w2b = Ws1[(k + 1) * DD + t];
#pragma unroll
        for (int gg = 0; gg < 4; ++gg) {
            float2 gv = *(const float2*)&gs[gg][k];
            a1[gg] = fmaf(gv.x, w1a, a1[gg]);
            a1[gg] = fmaf(gv.y, w1b, a1[gg]);
            a2[gg] = fmaf(gv.x, w2a, a2[gg]);
            a2[gg] = fmaf(gv.y, w2b, a2[gg]);
        }
    }
#pragma unroll
    for (int gg = 0; gg < 4; ++gg) {
        t1s[gg][t] = fmaxf(a1[gg] + br1[t], 0.f);
        gtop[gg][t] = a2[gg] + bs1[t];
    }
    __syncthreads();

    if (t < 4 * CC) {
        int gg = t / CC, c = t - gg * CC;
        float acc = br2[c];
        for (int d = 0; d < DD; ++d) acc = fmaf(t1s[gg][d], Wr2[d * CC + c], acc);
        logits[gg][c] = acc;
    }
    __syncthreads();
    if (t < 4 * CC) {
        int gg = t / CC, c = t - gg * CC;
        float m = -1e30f;
        for (int cc = 0; cc < CC; ++cc) m = fmaxf(m, logits[gg][cc]);
        float s = 0.f;
        for (int cc = 0; cc < CC; ++cc) s += __expf(logits[gg][cc] - m);
        probs[gg][c] = __expf(logits[gg][c] - m) / s;
    }
    __syncthreads();

    float wd = Ws2[t];
    float sacc[4];
#pragma unroll
    for (int gg = 0; gg < 4; ++gg) {
        float gt = gtop[gg][t];
        float acc = 0.f;
#pragma unroll
        for (int c = 0; c < CC; ++c)
            acc = fmaf(probs[gg][c], fmaxf(gt + EB[c * DD + t], 0.f), acc);
        sacc[gg] = acc * wd;
    }
#pragma unroll
    for (int gg = 0; gg < 4; ++gg) {
        float v = sacc[gg];
#pragma unroll
        for (int off = 32; off > 0; off >>= 1) v += __shfl_down(v, off, 64);
        if ((t & 63) == 0) red[t >> 6][gg] = v;
    }
    __syncthreads();
    if (t < 4)
        out[b0 + t] = red[0][t] + red[1][t] + red[2][t] + red[3][t] + bs2[0];
}

extern "C" void kernel_launch(void* const* d_in, const int* in_sizes, int n_in,
                              void* d_out, int out_size, void* d_ws, size_t ws_size,
                              hipStream_t stream)
{
    const float* x     = (const float*)d_in[0];
    const float* Win   = (const float*)d_in[3];
    const float* bin   = (const float*)d_in[4];
    const float* Wl    = (const float*)d_in[5];
    const float* Wr    = (const float*)d_in[6];
    const float* att   = (const float*)d_in[7];
    const float* Wr1   = (const float*)d_in[8];
    const float* br1   = (const float*)d_in[9];
    const float* Wr2   = (const float*)d_in[10];
    const float* br2   = (const float*)d_in[11];
    const float* Erecv = (const float*)d_in[12];
    const float* Ws1   = (const float*)d_in[13];
    const float* bs1   = (const float*)d_in[14];
    const float* Ws2   = (const float*)d_in[15];
    const float* bs2   = (const float*)d_in[16];
    float* out = (float*)d_out;

    short* Bh = (short*)d_ws;                       // [3][32][4096]
    short* Bl = Bh + (size_t)3 * 131072;
    float* g  = (float*)(Bl + (size_t)3 * 131072);  // [B][DD]
    float* EB = g + (size_t)BBATCH * DD;            // [CC][DD]

    k_prep<<<dim3(96 + CC), dim3(256), 0, stream>>>(Wl, Wr, Erecv, Ws1, Bh, Bl, EB);
    k_fused<<<dim3(NPAIR), dim3(1024), 0, stream>>>(x, Win, bin, Bh, Bl, att, g);
    k_head<<<dim3(256), dim3(256), 0, stream>>>(g, Wr1, br1, Wr2, br2,
                                                Ws1, bs1, Ws2, bs2, EB, out);
}

// Round 12
// 197.400 us; speedup vs baseline: 1.3771x; 1.0770x over previous
//
#include <hip/hip_runtime.h>

#define BBATCH 1024
#define NPAIR 512
#define PP 23      // nodes per frame
#define FF 14
#define DD 256
#define CC 23

#define HSTR 258            // hstate row stride (f32 words), even for float2
#define SLSTR 264           // sl/sro row stride (f16 halves)
#define RG 47472            // region start = hstate bytes (46*258*4)
#define SL_OFF   (RG)                 // [23][264] f16 = 12144 B
#define SRO_OFF  (RG + 12144)         // [23][264] f16
#define FRAG_OFF (RG)                 // 12288 f16 = 24576 B (GEMM phase, overlaps sl/sro)
#define S_OFF    (RG + 24576)         // [23][23][4] f32 = 8464 B
#define XS_OFF   (RG + 24576)         // [46][14] f32 (in_proj only, overlaps S)
#define SATT_OFF (RG + 33040)         // [264] f16 = 528 B
#define SMEM_SZ  (RG + 33568)         // 81040 B -> 2 blocks/CU (160 KB LDS)

// involutive 16B-block swizzle within a row (blocks of 8 halves)
#define SWZB(b) ((b) ^ (((b) >> 3) & 7))
#define SWZC(c) (SWZB((c) >> 3) * 8 + ((c) & 7))

typedef _Float16 f16;
typedef __attribute__((ext_vector_type(8))) _Float16 f16x8;
typedef __attribute__((ext_vector_type(4))) _Float16 f16x4;
typedef __attribute__((ext_vector_type(2))) _Float16 f16x2;
typedef __attribute__((ext_vector_type(8))) unsigned short u16x8;
typedef __attribute__((ext_vector_type(4))) float f32x4;

// ---------------- weight prep (blocks 0..95) + EB (blocks 96..118) ----------------
__global__ __launch_bounds__(256) void k_prep(const float* __restrict__ Wl,
    const float* __restrict__ Wr, const float* __restrict__ E,
    const float* __restrict__ Ws1, f16* __restrict__ Bf, float* __restrict__ EB)
{
    __shared__ float ws[DD][16];
    int t = threadIdx.x;
    if (blockIdx.x < 96) {
        int bid = blockIdx.x;            // l*32 + ntile
        int ll = bid >> 5, ntile = bid & 31;
        int n0 = ntile * 16;
        const float* W = (n0 < 256) ? (Wl + (size_t)ll * 65536) : (Wr + (size_t)ll * 65536);
        int c0 = n0 & 255;
        for (int kk = t >> 4; kk < DD; kk += 16)
            ws[kk][t & 15] = W[(size_t)kk * 256 + c0 + (t & 15)];
        __syncthreads();
        size_t base = (size_t)bid * 4096;
        for (int idx = t; idx < 4096; idx += 256) {
            int ks = idx >> 9;
            int lane = (idx >> 3) & 63;
            int e = idx & 7;
            int col = lane & 15;
            int k = ks * 32 + ((lane >> 4) << 3) + e;
            Bf[base + idx] = (f16)ws[k][col];
        }
    } else {
        int c = blockIdx.x - 96;
        float acc = 0.f;
        for (int k = 0; k < DD; ++k)
            acc = fmaf(E[c * DD + k], Ws1[(DD + k) * DD + t], acc);
        EB[c * DD + t] = acc;
    }
}

// ---------------- fully fused: in_proj + 3 GATv2 layers + readout ----------------
__global__ __launch_bounds__(1024, 8) void k_fused(
    const float* __restrict__ x, const float* __restrict__ Win,
    const float* __restrict__ bin, const f16* __restrict__ Bf,
    const float* __restrict__ att, float* __restrict__ g)
{
    __shared__ __align__(16) char smem[SMEM_SZ];
    float* hstate = (float*)smem;              // [46][258] f32, persistent
    f16* sl16   = (f16*)(smem + SL_OFF);
    f16* sro16  = (f16*)(smem + SRO_OFF);
    f16* frag   = (f16*)(smem + FRAG_OFF);     // packed A fragments
    float* S    = (float*)(smem + S_OFF);
    float* xs   = (float*)(smem + XS_OFF);
    f16* satt16 = (f16*)(smem + SATT_OFF);

    int t = threadIdx.x;
    int pair = blockIdx.x;

    // ---- stage x ----
    for (int idx = t; idx < 46 * FF; idx += 1024)
        xs[idx] = x[(size_t)pair * 46 * FF + idx];
    __syncthreads();

    // ---- in_proj: hstate f32 + frag f16 ----
    {
        int c2 = (t & 127) * 2, rp = t >> 7;
        float w0[FF], w1[FF];
#pragma unroll
        for (int f = 0; f < FF; ++f) {
            float2 wv = *(const float2*)&Win[f * DD + c2];
            w0[f] = wv.x; w1[f] = wv.y;
        }
        float2 bb = *(const float2*)&bin[c2];
        for (int r = rp; r < 48; r += 8) {
            float h0 = 0.f, h1 = 0.f;
            if (r < 46) {
                h0 = bb.x; h1 = bb.y;
#pragma unroll
                for (int f = 0; f < FF; ++f) {
                    float xv = xs[r * FF + f];
                    h0 = fmaf(xv, w0[f], h0);
                    h1 = fmaf(xv, w1[f], h1);
                }
                *(float2*)&hstate[r * HSTR + c2] = make_float2(h0, h1);
            }
            int off = ((r >> 4) * 8 + (c2 >> 5)) * 512 +
                      ((r & 15) + (((c2 & 31) >> 3) << 4)) * 8 + (c2 & 7);
            f16x2 hv2 = { (f16)h0, (f16)h1 };
            *(f16x2*)(frag + off) = hv2;
        }
    }

    int ln = t & 63, w = t >> 6;   // 16 waves

    // score mapping: t = i*32 + jh*16 + ch
    int sc_i  = t >> 5;
    int sc_jh = (t >> 4) & 1;
    int sc_ch = t & 15;
    int sc_hh = sc_ch >> 2;
    bool sc_act = (t < 736);
    int sb0 = SWZB(2 * sc_ch) * 8;
    int sb1 = SWZB(2 * sc_ch + 1) * 8;

    for (int layer = 0; layer < 3; ++layer) {
        if (t < DD) satt16[SWZC(t)] = (f16)att[layer * DD + t];

        if (layer > 0) {
            // convert hstate -> frag f16
            int c2 = (t & 127) * 2, rp = t >> 7;
            for (int r = rp; r < 48; r += 8) {
                float h0 = 0.f, h1 = 0.f;
                if (r < 46) {
                    float2 hv = *(const float2*)&hstate[r * HSTR + c2];
                    h0 = hv.x; h1 = hv.y;
                }
                int off = ((r >> 4) * 8 + (c2 >> 5)) * 512 +
                          ((r & 15) + (((c2 & 31) >> 3) << 4)) * 8 + (c2 & 7);
                f16x2 hv2 = { (f16)h0, (f16)h1 };
                *(f16x2*)(frag + off) = hv2;
            }
        }
        __syncthreads();   // frag + satt ready

        // ---- GEMM: single-term f16; 16 waves x 2 ntiles ----
        const f16* pB = Bf + (size_t)layer * 131072 + (size_t)(w * 2) * 4096 + ln * 8;
        const f16* lA = frag + ln * 8;

        f32x4 acc[3][2];
#pragma unroll
        for (int mt = 0; mt < 3; ++mt)
#pragma unroll
            for (int nt = 0; nt < 2; ++nt) acc[mt][nt] = (f32x4)0.0f;

#pragma unroll
        for (int ks = 0; ks < 8; ++ks) {
            f16x8 a0 = *(const f16x8*)(lA + (0 * 8 + ks) * 512);
            f16x8 a1 = *(const f16x8*)(lA + (1 * 8 + ks) * 512);
            f16x8 a2 = *(const f16x8*)(lA + (2 * 8 + ks) * 512);
#pragma unroll
            for (int nt = 0; nt < 2; ++nt) {
                f16x8 b = *(const f16x8*)(pB + (nt * 8 + ks) * 512);
                acc[0][nt] = __builtin_amdgcn_mfma_f32_16x16x32_f16(a0, b, acc[0][nt], 0, 0, 0);
                acc[1][nt] = __builtin_amdgcn_mfma_f32_16x16x32_f16(a1, b, acc[1][nt], 0, 0, 0);
                acc[2][nt] = __builtin_amdgcn_mfma_f32_16x16x32_f16(a2, b, acc[2][nt], 0, 0, 0);
            }
        }
        __syncthreads();   // frag dead; sl/sro/S usable

        // ---- per-frame attention ----
        for (int f = 0; f < 2; ++f) {
            // scatter acc -> swizzled f16 sl/sro
#pragma unroll
            for (int mt = 0; mt < 3; ++mt) {
                int rbase = mt * 16 + (ln >> 4) * 4;
#pragma unroll
                for (int nt = 0; nt < 2; ++nt) {
                    int col = w * 32 + nt * 16 + (ln & 15);
                    f16* dst = (col < 256) ? sl16 : sro16;
                    int cc = col & 255;
                    int sc = SWZC(cc);
#pragma unroll
                    for (int r2 = 0; r2 < 4; ++r2) {
                        int i = rbase + r2 - f * PP;
                        if (0 <= i && i < PP) dst[i * SLSTR + sc] = (f16)acc[mt][nt][r2];
                    }
                }
            }
            __syncthreads();

            // scores (linear term inlined; packed f16 math)
            if (sc_act) {
                f16x8 av0 = *(const f16x8*)(satt16 + sb0);
                f16x8 av1 = *(const f16x8*)(satt16 + sb1);
                const f16* srp = sro16 + sc_i * SLSTR;
                f16x8 rv0 = *(const f16x8*)(srp + sb0);
                f16x8 rv1 = *(const f16x8*)(srp + sb1);
                for (int j = sc_jh; j < PP; j += 2) {
                    const f16* slp = sl16 + j * SLSTR;
                    f16x8 l0 = *(const f16x8*)(slp + sb0);
                    f16x8 l1 = *(const f16x8*)(slp + sb1);
                    f16x8 v0 = l0 + rv0;
                    f16x8 v1 = l1 + rv1;
                    f16x8 q0 = (f16x8)((u16x8)v0 & (unsigned short)0x7FFF);
                    f16x8 q1 = (f16x8)((u16x8)v1 & (unsigned short)0x7FFF);
                    f16x8 sabs = av0 * q0; sabs += av1 * q1;
                    f16x8 slin = av0 * v0; slin += av1 * v1;
                    f16x8 tot = sabs * (f16)0.4f; tot += slin * (f16)0.6f;
                    f16x4 t4 = __builtin_shufflevector(tot, tot, 0, 1, 2, 3) +
                               __builtin_shufflevector(tot, tot, 4, 5, 6, 7);
                    float p = (float)t4[0] + (float)t4[1] + (float)t4[2] + (float)t4[3];
                    p += __shfl_xor(p, 1, 64);
                    p += __shfl_xor(p, 2, 64);
                    if ((t & 3) == 0)
                        S[(sc_i * PP + j) * 4 + sc_hh] = (j == sc_i) ? -1e30f : p;
                }
            }
            __syncthreads();

            // parallel softmax: 368 threads = (i, head, quad)
            if (t < 368) {
                int i = t >> 4, hh = (t >> 2) & 3, q = t & 3;
                float m = -1e30f;
                for (int j = q; j < PP; j += 4)
                    m = fmaxf(m, S[(i * PP + j) * 4 + hh]);
                m = fmaxf(m, __shfl_xor(m, 1, 64));
                m = fmaxf(m, __shfl_xor(m, 2, 64));
                float s = 0.f;
                for (int j = q; j < PP; j += 4)
                    s += __expf(S[(i * PP + j) * 4 + hh] - m);
                s += __shfl_xor(s, 1, 64);
                s += __shfl_xor(s, 2, 64);
                float inv = 1.f / s;
                for (int j = q; j < PP; j += 4) {
                    float* p = S + (i * PP + j) * 4 + hh;
                    *p = __expf(*p - m) * inv;
                }
            }
            __syncthreads();

            // aggregate + residual(f32) + elu -> hstate
            {
                int c = t & 255, ip = t >> 8, hh = c >> 6;
                int scn = SWZC(c);
                float slc[PP];
#pragma unroll
                for (int j = 0; j < PP; ++j) slc[j] = (float)sl16[j * SLSTR + scn];
                for (int i = ip; i < PP; i += 4) {
                    float accv = 0.f;
#pragma unroll
                    for (int j = 0; j < PP; ++j)
                        accv = fmaf(S[(i * PP + j) * 4 + hh], slc[j], accv);
                    int r = f * PP + i;
                    float res = accv + hstate[r * HSTR + c];
                    hstate[r * HSTR + c] = (res > 0.f) ? res : (__expf(res) - 1.f);
                }
            }
            __syncthreads();
        }
    }

    // ---- readout ----
    if (t < 512) {
        int f = t >> 8, c = t & 255;
        float s = 0.f;
#pragma unroll
        for (int i = 0; i < PP; ++i) s += hstate[(f * PP + i) * HSTR + c];
        g[(size_t)(pair * 2 + f) * DD + c] = s * (1.0f / 23.0f);
    }
}

// ---------------- head: 4 graphs per block ----------------
__global__ __launch_bounds__(256) void k_head(const float* __restrict__ g,
    const float* __restrict__ Wr1, const float* __restrict__ br1,
    const float* __restrict__ Wr2, const float* __restrict__ br2,
    const float* __restrict__ Ws1, const float* __restrict__ bs1,
    const float* __restrict__ Ws2, const float* __restrict__ bs2,
    const float* __restrict__ EB, float* __restrict__ out)
{
    __shared__ float gs[4][DD], t1s[4][DD], gtop[4][DD];
    __shared__ float logits[4][CC], probs[4][CC];
    __shared__ float red[4][4];
    int b0 = blockIdx.x * 4;
    int t = threadIdx.x;
    for (int idx = t; idx < 4 * DD; idx += 256)
        gs[idx >> 8][idx & 255] = g[(size_t)b0 * DD + idx];
    __syncthreads();

    float a1[4] = {0.f, 0.f, 0.f, 0.f}, a2[4] = {0.f, 0.f, 0.f, 0.f};
    for (int k = 0; k < DD; k += 2) {
        float w1a = Wr1[k * DD + t], w1b = Wr1[(k + 1) * DD + t];
        float w2a = Ws1[k * DD + t], w2b = Ws1[(k + 1) * DD + t];
#pragma unroll
        for (int gg = 0; gg < 4; ++gg) {
            float2 gv = *(const float2*)&gs[gg][k];
            a1[gg] = fmaf(gv.x, w1a, a1[gg]);
            a1[gg] = fmaf(gv.y, w1b, a1[gg]);
            a2[gg] = fmaf(gv.x, w2a, a2[gg]);
            a2[gg] = fmaf(gv.y, w2b, a2[gg]);
        }
    }
#pragma unroll
    for (int gg = 0; gg < 4; ++gg) {
        t1s[gg][t] = fmaxf(a1[gg] + br1[t], 0.f);
        gtop[gg][t] = a2[gg] + bs1[t];
    }
    __syncthreads();

    if (t < 4 * CC) {
        int gg = t / CC, c = t - gg * CC;
        float acc = br2[c];
        for (int d = 0; d < DD; ++d) acc = fmaf(t1s[gg][d], Wr2[d * CC + c], acc);
        logits[gg][c] = acc;
    }
    __syncthreads();
    if (t < 4 * CC) {
        int gg = t / CC, c = t - gg * CC;
        float m = -1e30f;
        for (int cc = 0; cc < CC; ++cc) m = fmaxf(m, logits[gg][cc]);
        float s = 0.f;
        for (int cc = 0; cc < CC; ++cc) s += __expf(logits[gg][cc] - m);
        probs[gg][c] = __expf(logits[gg][c] - m) / s;
    }
    __syncthreads();

    float wd = Ws2[t];
    float sacc[4];
#pragma unroll
    for (int gg = 0; gg < 4; ++gg) {
        float gt = gtop[gg][t];
        float acc = 0.f;
#pragma unroll
        for (int c = 0; c < CC; ++c)
            acc = fmaf(probs[gg][c], fmaxf(gt + EB[c * DD + t], 0.f), acc);
        sacc[gg] = acc * wd;
    }
#pragma unroll
    for (int gg = 0; gg < 4; ++gg) {
        float v = sacc[gg];
#pragma unroll
        for (int off = 32; off > 0; off >>= 1) v += __shfl_down(v, off, 64);
        if ((t & 63) == 0) red[t >> 6][gg] = v;
    }
    __syncthreads();
    if (t < 4)
        out[b0 + t] = red[0][t] + red[1][t] + red[2][t] + red[3][t] + bs2[0];
}

extern "C" void kernel_launch(void* const* d_in, const int* in_sizes, int n_in,
                              void* d_out, int out_size, void* d_ws, size_t ws_size,
                              hipStream_t stream)
{
    const float* x     = (const float*)d_in[0];
    const float* Win   = (const float*)d_in[3];
    const float* bin   = (const float*)d_in[4];
    const float* Wl    = (const float*)d_in[5];
    const float* Wr    = (const float*)d_in[6];
    const float* att   = (const float*)d_in[7];
    const float* Wr1   = (const float*)d_in[8];
    const float* br1   = (const float*)d_in[9];
    const float* Wr2   = (const float*)d_in[10];
    const float* br2   = (const float*)d_in[11];
    const float* Erecv = (const float*)d_in[12];
    const float* Ws1   = (const float*)d_in[13];
    const float* bs1   = (const float*)d_in[14];
    const float* Ws2   = (const float*)d_in[15];
    const float* bs2   = (const float*)d_in[16];
    float* out = (float*)d_out;

    f16* Bf   = (f16*)d_ws;                          // [3][32][4096] f16
    float* g  = (float*)(Bf + (size_t)3 * 131072);   // [B][DD]
    float* EB = g + (size_t)BBATCH * DD;             // [CC][DD]

    k_prep<<<dim3(96 + CC), dim3(256), 0, stream>>>(Wl, Wr, Erecv, Ws1, Bf, EB);
    k_fused<<<dim3(NPAIR), dim3(1024), 0, stream>>>(x, Win, bin, Bf, att, g);
    k_head<<<dim3(256), dim3(256), 0, stream>>>(g, Wr1, br1, Wr2, br2,
                                                Ws1, bs1, Ws2, bs2, EB, out);
}